// Round 8
// baseline (294.985 us; speedup 1.0000x reference)
//
#include <hip/hip_runtime.h>
#include <stdint.h>

typedef __attribute__((ext_vector_type(8))) short short8;
typedef __attribute__((ext_vector_type(4))) float f32x4;
typedef unsigned short ushort_t;

#define T_STEPS 10
#define BT  128                                 // batch rows per block
#define WPACK_BYTES (2048*1024)                 // 2048 chunks x 1 KiB
#define VBUF_OFF  WPACK_BYTES
#define HBF_OFF   (WPACK_BYTES + 8192)
#define H_ELEMS   (8192ull*T_STEPS*512)
#define HBF_BYTES (H_ELEMS*2)

typedef const __attribute__((address_space(1))) void gas_void;
typedef __attribute__((address_space(3))) void las_void;

__device__ __forceinline__ void gld_lds16(const void* g, void* l){
  __builtin_amdgcn_global_load_lds((gas_void*)g, (las_void*)l, 16, 0, 0);
}

#define VMW(N) asm volatile("s_waitcnt vmcnt(" #N ")" ::: "memory")

__device__ __forceinline__ unsigned int pk2(float x, float y){
  unsigned int bx = __float_as_uint(x), by = __float_as_uint(y);
  bx = (bx + 0x7FFFu + ((bx>>16)&1u)) >> 16;     // RNE fp32->bf16
  by = (by + 0x7FFFu + ((by>>16)&1u)) >> 16;
  return bx | (by<<16);
}
__device__ __forceinline__ float sigf(float x){ return 1.f/(1.f + __expf(-x)); }
__device__ __forceinline__ float tanh_(float x){
  x = fminf(fmaxf(x, -15.f), 15.f);
  float e = __expf(2.f*x);
  return (e - 1.f)/(e + 1.f);
}

// ---- K0a: pack W_hh [2048][512] fp32 -> bf16 B-fragment chunks -------------
// chunk = ((jb*8 + jt)*4 + g)*16 + kc ; in-chunk lane = khi*16 + jl
__global__ __launch_bounds__(256) void k_pack(const float* __restrict__ Whh,
                                              ushort_t* __restrict__ wp){
  int id  = blockIdx.x*256 + threadIdx.x;
  int row = id >> 6;
  int ko  = (id & 63) * 8;
  const float* p = Whh + row*512 + ko;
  float4 a = *(const float4*)p, b = *(const float4*)(p+4);
  uint4 v;
  v.x = pk2(a.x,a.y); v.y = pk2(a.z,a.w);
  v.z = pk2(b.x,b.y); v.w = pk2(b.z,b.w);
  int g = row >> 9, j = row & 511;
  int jb = j >> 7, jt = (j >> 4) & 7, jl = j & 15;
  int kc = ko >> 5, khi = (ko >> 3) & 3, lane = khi*16 + jl;
  int chunk = ((jb*8 + jt)*4 + g)*16 + kc;
  *(uint4*)(wp + chunk*512 + lane*8) = v;
}

// ---- K0b -------------------------------------------------------------------
__global__ __launch_bounds__(256) void k_v(const float* __restrict__ fc1w,
                                           const float* __restrict__ fc1b,
                                           const float* __restrict__ fc2w,
                                           const float* __restrict__ fc2b,
                                           float* __restrict__ vout,
                                           float* __restrict__ bias0){
  __shared__ float red[4][64];
  int tid = threadIdx.x;
  if (blockIdx.x < 16){
    int j  = blockIdx.x*64 + (tid & 63);
    int hc = tid >> 6;
    float s = 0.f;
    for (int hh = hc*128; hh < hc*128 + 128; ++hh)
      s += fc2w[hh] * fc1w[hh*1024 + j];
    red[hc][tid & 63] = s;
    __syncthreads();
    if (tid < 64)
      vout[blockIdx.x*64 + tid] = red[0][tid]+red[1][tid]+red[2][tid]+red[3][tid];
  } else {
    if (tid < 64){
      float s = 0.f;
      for (int i = 0; i < 8; ++i){ int hh = i*64 + tid; s += fc2w[hh]*fc1b[hh]; }
      for (int m = 32; m; m >>= 1) s += __shfl_xor(s, m);
      if (tid == 0) *bias0 = s + fc2b[0];
    }
  }
}

// ---- K2 --------------------------------------------------------------------
__global__ __launch_bounds__(512) void k_init(const float* __restrict__ h,
                                              const float* __restrict__ v,
                                              const float* __restrict__ bias0,
                                              float* __restrict__ out){
  int w = threadIdx.x >> 6, lane = threadIdx.x & 63;
  float b0v = *bias0;
  const float* v2 = v + 512;
  for (int r = 0; r < 8; ++r){
    int b = blockIdx.x*64 + w*8 + r;
    const float* hp = h + ((size_t)b*T_STEPS + 9)*512 + lane*8;
    float4 x0 = *(const float4*)hp, x1 = *(const float4*)(hp+4);
    const float* vp = v2 + lane*8;
    float4 w0 = *(const float4*)vp, w1 = *(const float4*)(vp+4);
    float s = x0.x*w0.x + x0.y*w0.y + x0.z*w0.z + x0.w*w0.w
            + x1.x*w1.x + x1.y*w1.y + x1.z*w1.z + x1.w*w1.w;
    for (int m = 32; m; m >>= 1) s += __shfl_xor(s, m);
    if (lane == 0) out[b] = s + b0v;
  }
}

// ---- K0c: h fp32 -> bf16. grid = H_ELEMS/16/256 = 10240 --------------------
__global__ __launch_bounds__(256) void k_prep(const float* __restrict__ h,
                                              ushort_t* __restrict__ hbf){
  size_t id = (size_t)blockIdx.x*256 + threadIdx.x;
  if (id*16 >= H_ELEMS) return;
  const float* p = h + id*16;
  float4 a = *(const float4*)p,     b = *(const float4*)(p+4);
  float4 c = *(const float4*)(p+8), d = *(const float4*)(p+12);
  uint4 lo, hi;
  lo.x = pk2(a.x,a.y); lo.y = pk2(a.z,a.w); lo.z = pk2(b.x,b.y); lo.w = pk2(b.z,b.w);
  hi.x = pk2(c.x,c.y); hi.y = pk2(c.z,c.w); hi.z = pk2(d.x,d.y); hi.w = pk2(d.z,d.w);
  uint4* qq = (uint4*)(hbf + id*16);
  qq[0] = lo; qq[1] = hi;
}

// ============================================================================
// K1 (PREP): ring-4 LDS, depth-3 prefetch, counted vmcnt, raw barriers (T3+T4)
// slice s: t = (s<160)? s>>4 : 9 ; kc = s&15. A offset = 64*s bytes (s<160),
// with a one-time -1024B correction at s==160.
// ============================================================================
__global__ __launch_bounds__(512) void k_main_p(
    const ushort_t* __restrict__ hbf, const float* __restrict__ y,
    const float* __restrict__ Wih, const float* __restrict__ bih,
    const float* __restrict__ bhh,
    const ushort_t* __restrict__ wpack, const float* __restrict__ v1,
    float* __restrict__ out)
{
  __shared__ __align__(16) ushort_t ring[4][16384];   // 4 x {A:8KB | W:24KB}
  __shared__ float ys[BT*T_STEPS];                    // 5 KiB

  int tid = threadIdx.x;
  int w = tid >> 6, lane = tid & 63, lhi = lane >> 4, llo = lane & 15;
  int mh = w & 1, wj = w >> 1;
  int bid = blockIdx.x;
  int xcd = bid & 7, q = bid >> 3;
  int tile = xcd*8 + (q >> 2), jb = q & 3;
  int b0 = tile * BT;

  int cb[3];
#pragma unroll
  for (int i = 0; i < 3; ++i){
    int cw = w*3 + i, g = cw >> 3, jt = cw & 7;
    cb[i] = ((jb*8 + jt)*4 + g)*16;
  }
  int cbo = ((jb*8 + w)*4 + 3)*16;

  int arow = w*16 + (lane >> 2), qa = lane & 3;
  const ushort_t* asrc = hbf + ((size_t)(b0 + arow)*T_STEPS)*512 + qa*8;

  float bias2[4][2], wihv[4][2];
#pragma unroll
  for (int g = 0; g < 4; ++g)
#pragma unroll
    for (int n = 0; n < 2; ++n){
      int col = g*512 + jb*128 + (wj*2+n)*16 + llo;
      bias2[g][n] = bih[col] + bhh[col];
      wihv[g][n]  = Wih[col];
    }
  float v1v[2];
#pragma unroll
  for (int n = 0; n < 2; ++n) v1v[n] = v1[jb*128 + (wj*2+n)*16 + llo];

  for (int i = tid; i < BT*T_STEPS; i += 512)
    ys[i] = y[(size_t)b0*T_STEPS + i];

  // prologue: issue slices 0..2, full drain once, barrier
#pragma unroll
  for (int k = 0; k < 3; ++k){
    ushort_t* base = ring[k];
    gld_lds16(asrc, base + w*512);
#pragma unroll
    for (int i = 0; i < 3; ++i)
      gld_lds16(wpack + (size_t)(cb[i] + k)*512 + lane*8,
                base + 4096 + (w*3+i)*512);
    asrc += 32;
  }
  asm volatile("s_waitcnt vmcnt(0) lgkmcnt(0)" ::: "memory");
  __builtin_amdgcn_sched_barrier(0);
  __builtin_amdgcn_s_barrier();
  __builtin_amdgcn_sched_barrier(0);

  float cst[4][2][4];
  f32x4 acc[4][3][2];
  f32x4 acco[4][2];
#pragma unroll
  for (int m = 0; m < 4; ++m)
#pragma unroll
    for (int n = 0; n < 2; ++n){
#pragma unroll
      for (int r = 0; r < 4; ++r) cst[m][n][r] = 0.f;
#pragma unroll
      for (int g = 0; g < 3; ++g) acc[m][g][n] = (f32x4){0.f,0.f,0.f,0.f};
      acco[m][n] = (f32x4){0.f,0.f,0.f,0.f};
    }

#pragma unroll 1
  for (int s = 0; s < 176; ++s){
    // ---- issue stage(s+3) ----
    int ns = s + 3;
    if (ns < 176){
      if (ns == 160) asrc -= 512;           // phase boundary: 64*160B -> 9216B
      ushort_t* base = ring[ns & 3];
      gld_lds16(asrc, base + w*512);
      int kc = ns & 15;
      if (ns < 160){
#pragma unroll
        for (int i = 0; i < 3; ++i)
          gld_lds16(wpack + (size_t)(cb[i] + kc)*512 + lane*8,
                    base + 4096 + (w*3+i)*512);
      } else {
        gld_lds16(wpack + (size_t)(cbo + kc)*512 + lane*8,
                  base + 4096 + w*512);
      }
      asrc += 32;
    }

    // ---- compute slice s ----
    const ushort_t* ab = ring[s & 3];
    const ushort_t* wb = ab + 4096;
    short8 af[4];
#pragma unroll
    for (int m = 0; m < 4; ++m)
      af[m] = *(const short8*)(ab + (mh*64 + m*16 + llo)*32 + lhi*8);

    if (s < 160){
      short8 wf[3][2];
#pragma unroll
      for (int g = 0; g < 3; ++g)
#pragma unroll
        for (int n = 0; n < 2; ++n)
          wf[g][n] = *(const short8*)(wb + ((g*8 + wj*2 + n) << 9) + lane*8);
#pragma unroll
      for (int g = 0; g < 3; ++g)
#pragma unroll
        for (int n = 0; n < 2; ++n)
#pragma unroll
          for (int m = 0; m < 4; ++m)
            acc[m][g][n] = __builtin_amdgcn_mfma_f32_16x16x32_bf16(
                af[m], wf[g][n], acc[m][g][n], 0, 0, 0);
      if ((s & 15) == 15){
        int t = s >> 4;
#pragma unroll
        for (int m = 0; m < 4; ++m)
#pragma unroll
          for (int r = 0; r < 4; ++r){
            float yr = ys[(mh*64 + m*16 + lhi*4 + r)*T_STEPS + t];
#pragma unroll
            for (int n = 0; n < 2; ++n){
              float pi = acc[m][0][n][r] + fmaf(yr, wihv[0][n], bias2[0][n]);
              float pf = acc[m][1][n][r] + fmaf(yr, wihv[1][n], bias2[1][n]);
              float pg = acc[m][2][n][r] + fmaf(yr, wihv[2][n], bias2[2][n]);
              cst[m][n][r] = sigf(pf)*cst[m][n][r] + sigf(pi)*tanh_(pg);
            }
          }
#pragma unroll
        for (int m = 0; m < 4; ++m)
#pragma unroll
          for (int g = 0; g < 3; ++g)
#pragma unroll
            for (int n = 0; n < 2; ++n) acc[m][g][n] = (f32x4){0.f,0.f,0.f,0.f};
      }
    } else {
      short8 wo[2];
#pragma unroll
      for (int n = 0; n < 2; ++n)
        wo[n] = *(const short8*)(wb + ((wj*2 + n) << 9) + lane*8);
#pragma unroll
      for (int n = 0; n < 2; ++n)
#pragma unroll
        for (int m = 0; m < 4; ++m)
          acco[m][n] = __builtin_amdgcn_mfma_f32_16x16x32_bf16(
              af[m], wo[n], acco[m][n], 0, 0, 0);
    }

    // ---- counted drain (ensure slice s+1 landed) + raw barrier ----
    // in-flight after issue: slices s+1,s+2,s+3 (4 VMEM if <160, 2 if >=160)
    if (s <= 156)      { VMW(8); }
    else if (s == 157) { VMW(6); }
    else if (s <= 172) { VMW(4); }
    else if (s == 173) { VMW(2); }
    else               { VMW(0); }
    __builtin_amdgcn_sched_barrier(0);
    __builtin_amdgcn_s_barrier();
    __builtin_amdgcn_sched_barrier(0);
  }

  // ---- epilogue ----
#pragma unroll
  for (int m = 0; m < 4; ++m)
#pragma unroll
    for (int r = 0; r < 4; ++r){
      float yr = ys[(mh*64 + m*16 + lhi*4 + r)*T_STEPS + 9];
      float val = 0.f;
#pragma unroll
      for (int n = 0; n < 2; ++n){
        float po = acco[m][n][r] + fmaf(yr, wihv[3][n], bias2[3][n]);
        val += sigf(po)*tanh_(cst[m][n][r])*v1v[n];
      }
      val += __shfl_xor(val, 1);
      val += __shfl_xor(val, 2);
      val += __shfl_xor(val, 4);
      val += __shfl_xor(val, 8);
      if (llo == 0)
        atomicAdd(&out[b0 + mh*64 + m*16 + lhi*4 + r], val);
    }
}

// ============================================================================
// K1 fallback (!PREP): 2-buffer, plain __syncthreads (R7-proven structure)
// ============================================================================
__global__ __launch_bounds__(512) void k_main_f(
    const float* __restrict__ h, const float* __restrict__ y,
    const float* __restrict__ Wih, const float* __restrict__ bih,
    const float* __restrict__ bhh,
    const ushort_t* __restrict__ wpack, const float* __restrict__ v1,
    float* __restrict__ out)
{
  __shared__ __align__(16) ushort_t ring[2][16384];
  __shared__ float ys[BT*T_STEPS];

  int tid = threadIdx.x;
  int w = tid >> 6, lane = tid & 63, lhi = lane >> 4, llo = lane & 15;
  int mh = w & 1, wj = w >> 1;
  int bid = blockIdx.x;
  int xcd = bid & 7, q = bid >> 3;
  int tile = xcd*8 + (q >> 2), jb = q & 3;
  int b0 = tile * BT;

  float bias2[4][2], wihv[4][2];
#pragma unroll
  for (int g = 0; g < 4; ++g)
#pragma unroll
    for (int n = 0; n < 2; ++n){
      int col = g*512 + jb*128 + (wj*2+n)*16 + llo;
      bias2[g][n] = bih[col] + bhh[col];
      wihv[g][n]  = Wih[col];
    }
  float v1v[2];
#pragma unroll
  for (int n = 0; n < 2; ++n) v1v[n] = v1[jb*128 + (wj*2+n)*16 + llo];

  for (int i = tid; i < BT*T_STEPS; i += 512)
    ys[i] = y[(size_t)b0*T_STEPS + i];

  auto stage = [&](ushort_t* base, int s){
    int t  = (s < 160) ? (s >> 4) : 9;
    int kc = s & 15;
    {
      int row = tid >> 2, qa2 = tid & 3;
      const float* p = h + ((size_t)(b0+row)*T_STEPS + t)*512 + kc*32 + qa2*8;
      float4 x0 = *(const float4*)p, x1 = *(const float4*)(p+4);
      uint4 pk;
      pk.x = pk2(x0.x,x0.y); pk.y = pk2(x0.z,x0.w);
      pk.z = pk2(x1.x,x1.y); pk.w = pk2(x1.z,x1.w);
      *(uint4*)(base + row*32 + qa2*8) = pk;
    }
    if (s < 160){
#pragma unroll
      for (int i = 0; i < 3; ++i){
        int cw = w*3 + i, g = cw >> 3, jt = cw & 7;
        gld_lds16(wpack + ((size_t)((jb*8+jt)*4+g)*16 + kc)*512 + lane*8,
                  base + 4096 + cw*512);
      }
    } else {
      gld_lds16(wpack + ((size_t)((jb*8+w)*4+3)*16 + kc)*512 + lane*8,
                base + 4096 + w*512);
    }
  };

  stage(ring[0], 0);
  __syncthreads();

  float cst[4][2][4];
  f32x4 acc[4][3][2];
  f32x4 acco[4][2];
#pragma unroll
  for (int m = 0; m < 4; ++m)
#pragma unroll
    for (int n = 0; n < 2; ++n){
#pragma unroll
      for (int r = 0; r < 4; ++r) cst[m][n][r] = 0.f;
#pragma unroll
      for (int g = 0; g < 3; ++g) acc[m][g][n] = (f32x4){0.f,0.f,0.f,0.f};
      acco[m][n] = (f32x4){0.f,0.f,0.f,0.f};
    }

#pragma unroll 1
  for (int s = 0; s < 176; ++s){
    if (s + 1 < 176) stage(ring[(s+1)&1], s+1);

    const ushort_t* ab = ring[s & 1];
    const ushort_t* wb = ab + 4096;
    short8 af[4];
#pragma unroll
    for (int m = 0; m < 4; ++m)
      af[m] = *(const short8*)(ab + (mh*64 + m*16 + llo)*32 + lhi*8);

    if (s < 160){
      short8 wf[3][2];
#pragma unroll
      for (int g = 0; g < 3; ++g)
#pragma unroll
        for (int n = 0; n < 2; ++n)
          wf[g][n] = *(const short8*)(wb + ((g*8 + wj*2 + n) << 9) + lane*8);
#pragma unroll
      for (int g = 0; g < 3; ++g)
#pragma unroll
        for (int n = 0; n < 2; ++n)
#pragma unroll
          for (int m = 0; m < 4; ++m)
            acc[m][g][n] = __builtin_amdgcn_mfma_f32_16x16x32_bf16(
                af[m], wf[g][n], acc[m][g][n], 0, 0, 0);
      if ((s & 15) == 15){
        int t = s >> 4;
#pragma unroll
        for (int m = 0; m < 4; ++m)
#pragma unroll
          for (int r = 0; r < 4; ++r){
            float yr = ys[(mh*64 + m*16 + lhi*4 + r)*T_STEPS + t];
#pragma unroll
            for (int n = 0; n < 2; ++n){
              float pi = acc[m][0][n][r] + fmaf(yr, wihv[0][n], bias2[0][n]);
              float pf = acc[m][1][n][r] + fmaf(yr, wihv[1][n], bias2[1][n]);
              float pg = acc[m][2][n][r] + fmaf(yr, wihv[2][n], bias2[2][n]);
              cst[m][n][r] = sigf(pf)*cst[m][n][r] + sigf(pi)*tanh_(pg);
            }
          }
#pragma unroll
        for (int m = 0; m < 4; ++m)
#pragma unroll
          for (int g = 0; g < 3; ++g)
#pragma unroll
            for (int n = 0; n < 2; ++n) acc[m][g][n] = (f32x4){0.f,0.f,0.f,0.f};
      }
    } else {
      short8 wo[2];
#pragma unroll
      for (int n = 0; n < 2; ++n)
        wo[n] = *(const short8*)(wb + ((wj*2 + n) << 9) + lane*8);
#pragma unroll
      for (int n = 0; n < 2; ++n)
#pragma unroll
        for (int m = 0; m < 4; ++m)
          acco[m][n] = __builtin_amdgcn_mfma_f32_16x16x32_bf16(
              af[m], wo[n], acco[m][n], 0, 0, 0);
    }
    __syncthreads();
  }

#pragma unroll
  for (int m = 0; m < 4; ++m)
#pragma unroll
    for (int r = 0; r < 4; ++r){
      float yr = ys[(mh*64 + m*16 + lhi*4 + r)*T_STEPS + 9];
      float val = 0.f;
#pragma unroll
      for (int n = 0; n < 2; ++n){
        float po = acco[m][n][r] + fmaf(yr, wihv[3][n], bias2[3][n]);
        val += sigf(po)*tanh_(cst[m][n][r])*v1v[n];
      }
      val += __shfl_xor(val, 1);
      val += __shfl_xor(val, 2);
      val += __shfl_xor(val, 4);
      val += __shfl_xor(val, 8);
      if (llo == 0)
        atomicAdd(&out[b0 + mh*64 + m*16 + lhi*4 + r], val);
    }
}

extern "C" void kernel_launch(void* const* d_in, const int* in_sizes, int n_in,
                              void* d_out, int out_size, void* d_ws, size_t ws_size,
                              hipStream_t stream){
  (void)in_sizes; (void)n_in; (void)out_size;
  const float* h    = (const float*)d_in[0];
  const float* y    = (const float*)d_in[1];
  // d_in[2..7] = attention weights: mathematically dead (softmax over size-1 dim == 1)
  const float* Wih  = (const float*)d_in[8];
  const float* Whh  = (const float*)d_in[9];
  const float* bih  = (const float*)d_in[10];
  const float* bhh  = (const float*)d_in[11];
  const float* fc1w = (const float*)d_in[12];
  const float* fc1b = (const float*)d_in[13];
  const float* fc2w = (const float*)d_in[14];
  const float* fc2b = (const float*)d_in[15];
  float* out = (float*)d_out;

  ushort_t* wpack = (ushort_t*)d_ws;
  float* vbuf  = (float*)((char*)d_ws + VBUF_OFF);
  float* bias0 = vbuf + 1024;
  ushort_t* hbf = (ushort_t*)((char*)d_ws + HBF_OFF);
  bool prep = ws_size >= (size_t)HBF_OFF + HBF_BYTES;

  k_pack<<<512, 256, 0, stream>>>(Whh, wpack);
  k_v<<<17, 256, 0, stream>>>(fc1w, fc1b, fc2w, fc2b, vbuf, bias0);
  if (prep){
    int prep_blocks = (int)(H_ELEMS / 16 / 256);   // = 10240, exact
    k_prep<<<prep_blocks, 256, 0, stream>>>(h, hbf);
  }
  k_init<<<128, 512, 0, stream>>>(h, vbuf, bias0, out);
  if (prep)
    k_main_p<<<256, 512, 0, stream>>>(hbf, y, Wih, bih, bhh, wpack, vbuf, out);
  else
    k_main_f<<<256, 512, 0, stream>>>(h, y, Wih, bih, bhh, wpack, vbuf, out);
}